// Round 4
// baseline (1233.089 us; speedup 1.0000x reference)
//
#include <hip/hip_runtime.h>
#include <stdint.h>

// VectorQuantizer — z:(16,256,64,64) f32 -> 65536 rows of 256; emb:(1024,256) f32.
// d_out: q[16777216] | vq_loss[1] | idx_as_float[65536]
//
// R4: dq-specialized argmin. z in LDS (DMA, linear, conflict-free broadcast
// reads); e read directly from global (L2-resident 1MB codebook, fully-
// coalesced 64B-line consumption by dq-quads); no barriers in main loop.
// R3 lesson: e-LDS reads were 4-way bank-conflicted (2e8 cycles) and LDS BW
// was near-critical at 10.7 FMA/read; this structure is 32 FMA/LDS-read.

#define WAITVM(N) asm volatile("s_waitcnt vmcnt(" #N ")" ::: "memory")

__device__ __forceinline__ void gload16(const float* gp, float* lp) {
    __builtin_amdgcn_global_load_lds(
        (const __attribute__((address_space(1))) void*)gp,
        (__attribute__((address_space(3))) void*)lp, 16, 0, 0);
}

// ---------------- kernel 0: embedding row norms ----------------
__global__ __launch_bounds__(256)
void enorm_kernel(const float* __restrict__ emb, float* __restrict__ enorm) {
    const int wv = threadIdx.x >> 6, ln = threadIdx.x & 63;
    const int k = blockIdx.x * 4 + wv;
    const float4 v = *reinterpret_cast<const float4*>(emb + (size_t)k * 256 + ln * 4);
    float s = v.x * v.x + v.y * v.y + v.z * v.z + v.w * v.w;
#pragma unroll
    for (int off = 32; off > 0; off >>= 1) s += __shfl_xor(s, off);
    if (ln == 0) enorm[k] = s;
}

// ---------------- kernel 1: argmin (dq-specialized) ----------------
// 256 thr = 4 waves. Wave wv owns rows wv*16+m (m=0..15).
// Lane: dq = tid&3 (d-quarter), tx = (tid>>2)&15 (code lane).
// Per chunk kc (128 codes): thread's codes = kc*128 + c*16 + tx, c=0..7.
// acc[m][c] = partial dot over d ≡ {dc*16 + dq*4 .. +3}; quad-shuffle combines.
__global__ __launch_bounds__(256, 2)
void argmin_kernel(const float* __restrict__ z, const float* __restrict__ emb,
                   const float* __restrict__ enorm_g, float* __restrict__ idx_out) {
    __shared__ float z_lds[16384];   // [row][d] linear, 64 KB
    __shared__ float znbuf[64];

    const int tid = threadIdx.x;
    const int dq = tid & 3;
    const int tx = (tid >> 2) & 15;
    const int wv = tid >> 6;
    const int ln = tid & 63;

    const float* zblk = z + (size_t)blockIdx.x * 16384;

    // ---- DMA z tile to LDS (linear dest = linear source; wave-uniform base + ln*16) ----
#pragma unroll
    for (int c = 0; c < 16; ++c) {
        const int off = c * 1024 + wv * 256 + ln * 4;
        gload16(zblk + off, &z_lds[off]);
    }

    // ---- per-row |z|^2 from global (hits L2; overlaps DMA) ----
#pragma unroll
    for (int it = 0; it < 16; ++it) {
        const int r = it * 4 + wv;
        const float4 v = *reinterpret_cast<const float4*>(zblk + r * 256 + ln * 4);
        float s = fmaf(v.x, v.x, fmaf(v.y, v.y, fmaf(v.z, v.z, v.w * v.w)));
#pragma unroll
        for (int o = 32; o > 0; o >>= 1) s += __shfl_xor(s, o);
        if (ln == 0) znbuf[r] = s;
    }

    WAITVM(0);
    __syncthreads();   // z_lds + znbuf ready; no barriers after this point

    float best[16];
    int   bidx[16];
#pragma unroll
    for (int m = 0; m < 16; ++m) { best[m] = 3.4e38f; bidx[m] = 0; }

    const int zbase = wv * 4096 + dq * 4;   // row wv*16, d-quarter dq

#pragma unroll 1
    for (int kc = 0; kc < 8; ++kc) {
        float acc[16][8];
#pragma unroll
        for (int m = 0; m < 16; ++m)
#pragma unroll
            for (int c = 0; c < 8; ++c) acc[m][c] = 0.f;

        float en[8];
#pragma unroll
        for (int c = 0; c < 8; ++c) en[c] = enorm_g[kc * 128 + c * 16 + tx];

#pragma unroll 1
        for (int dc = 0; dc < 16; ++dc) {
            // e: 8 float4 loads from global; each 64B line is consumed by a dq-quad
            float4 e[8];
#pragma unroll
            for (int c = 0; c < 8; ++c)
                e[c] = *reinterpret_cast<const float4*>(
                    emb + (size_t)(kc * 128 + c * 16 + tx) * 256 + dc * 16 + dq * 4);
#pragma unroll
            for (int m = 0; m < 16; ++m) {
                const float4 a = *reinterpret_cast<const float4*>(
                    &z_lds[zbase + m * 256 + dc * 16]);
#pragma unroll
                for (int c = 0; c < 8; ++c) {
                    acc[m][c] = fmaf(a.x, e[c].x, acc[m][c]);
                    acc[m][c] = fmaf(a.y, e[c].y, acc[m][c]);
                    acc[m][c] = fmaf(a.z, e[c].z, acc[m][c]);
                    acc[m][c] = fmaf(a.w, e[c].w, acc[m][c]);
                }
            }
        }

        // ---- chunk epilogue: combine dq partials (quad DPP), dist, argmin ----
#pragma unroll
        for (int m = 0; m < 16; ++m) {
            const float znm = znbuf[wv * 16 + m];
#pragma unroll
            for (int c = 0; c < 8; ++c) {
                float dot = acc[m][c];
                dot += __shfl_xor(dot, 1);
                dot += __shfl_xor(dot, 2);
                const float dist = fmaf(-2.f, dot, znm + en[c]);
                const int col = kc * 128 + c * 16 + tx;   // ascending scan order
                if (dist < best[m]) { best[m] = dist; bidx[m] = col; }
            }
        }
    }

    // ---- cross-tx butterfly (lane bits 2..5) with lowest-index tie-break ----
#pragma unroll
    for (int m = 0; m < 16; ++m) {
#pragma unroll
        for (int off = 4; off < 64; off <<= 1) {
            const float ov = __shfl_xor(best[m], off);
            const int   oi = __shfl_xor(bidx[m], off);
            if (ov < best[m] || (ov == best[m] && oi < bidx[m])) {
                best[m] = ov; bidx[m] = oi;
            }
        }
    }
    if (ln == 0) {
        float* o = idx_out + (size_t)blockIdx.x * 64 + wv * 16;
#pragma unroll
        for (int m = 0; m < 16; ++m) o[m] = (float)bidx[m];
    }
}

// ---------------- kernel 2: gather + quantized output + loss partials ----------------
__global__ __launch_bounds__(256)
void gather_kernel(const float* __restrict__ z, const float* __restrict__ emb,
                   const float* __restrict__ idx_f, float* __restrict__ q_out,
                   float* __restrict__ partials) {
    const int wv = threadIdx.x >> 6, ln = threadIdx.x & 63;
    float lsum = 0.f;
#pragma unroll
    for (int i = 0; i < 16; ++i) {
        const size_t row = (size_t)blockIdx.x * 64 + i * 4 + wv;
        const int kidx = (int)idx_f[row];
        const float4 e4 = *reinterpret_cast<const float4*>(emb + (size_t)kidx * 256 + ln * 4);
        const float4 z4 = *reinterpret_cast<const float4*>(z + row * 256 + ln * 4);
        *reinterpret_cast<float4*>(q_out + row * 256 + ln * 4) = e4;  // quantized_st == quantized
        const float dx = e4.x - z4.x, dy = e4.y - z4.y, dz = e4.z - z4.z, dw = e4.w - z4.w;
        lsum += dx * dx + dy * dy + dz * dz + dw * dw;
    }
#pragma unroll
    for (int off = 32; off > 0; off >>= 1) lsum += __shfl_xor(lsum, off);
    __shared__ float red[4];
    if (ln == 0) red[wv] = lsum;
    __syncthreads();
    if (threadIdx.x == 0) partials[blockIdx.x] = red[0] + red[1] + red[2] + red[3];
}

// ---------------- kernel 3: deterministic loss reduction ----------------
__global__ __launch_bounds__(256)
void loss_kernel(const float* __restrict__ partials, float* __restrict__ loss_out) {
    const int tid = threadIdx.x;
    float s = partials[tid] + partials[tid + 256] + partials[tid + 512] + partials[tid + 768];
#pragma unroll
    for (int off = 32; off > 0; off >>= 1) s += __shfl_xor(s, off);
    __shared__ float red[4];
    if ((tid & 63) == 0) red[tid >> 6] = s;
    __syncthreads();
    if (tid == 0)
        loss_out[0] = (red[0] + red[1] + red[2] + red[3]) * (1.25f / 16777216.0f);
}

extern "C" void kernel_launch(void* const* d_in, const int* in_sizes, int n_in,
                              void* d_out, int out_size, void* d_ws, size_t ws_size,
                              hipStream_t stream) {
    const float* z   = (const float*)d_in[0];
    const float* emb = (const float*)d_in[1];
    float* out      = (float*)d_out;
    float* q_out    = out;                       // 16,777,216 floats
    float* loss_out = out + 16777216;            // 1 float
    float* idx_out  = out + 16777217;            // 65,536 floats
    float* enorm    = (float*)d_ws;              // 1024 floats
    float* partials = (float*)d_ws + 1024;       // 1024 floats

    enorm_kernel<<<256, 256, 0, stream>>>(emb, enorm);
    argmin_kernel<<<1024, 256, 0, stream>>>(z, emb, enorm, idx_out);
    gather_kernel<<<1024, 256, 0, stream>>>(z, emb, idx_out, q_out, partials);
    loss_kernel<<<1, 256, 0, stream>>>(partials, loss_out);
}

// Round 5
// 819.122 us; speedup vs baseline: 1.5054x; 1.5054x over previous
//
#include <hip/hip_runtime.h>
#include <stdint.h>

// VectorQuantizer — z:(16,256,64,64) f32 -> 65536 rows of 256; emb:(1024,256) f32.
// d_out: q[16777216] | vq_loss[1] | idx_as_float[65536]
//
// R5: R4's dq-specialized structure (z in LDS via DMA, broadcast reads, e from
// global/L2, zero main-loop barriers) with the register budget fixed:
//  - KCHUNK=64 -> acc[16][4] = 64 VGPRs (R4's acc[16][8]=128 + lb(256,2) cap
//    of 128 VGPRs forced a 1.4 GB scratch spill: WRITE_SIZE 1.37e6 KB).
//  - __launch_bounds__(256,1): VGPR cap 512. Occupancy is LDS-capped at
//    2 blocks/CU (64 KB z-tile) regardless, so no spill and no occupancy loss.

#define WAITVM(N) asm volatile("s_waitcnt vmcnt(" #N ")" ::: "memory")

__device__ __forceinline__ void gload16(const float* gp, float* lp) {
    __builtin_amdgcn_global_load_lds(
        (const __attribute__((address_space(1))) void*)gp,
        (__attribute__((address_space(3))) void*)lp, 16, 0, 0);
}

// ---------------- kernel 0: embedding row norms ----------------
__global__ __launch_bounds__(256)
void enorm_kernel(const float* __restrict__ emb, float* __restrict__ enorm) {
    const int wv = threadIdx.x >> 6, ln = threadIdx.x & 63;
    const int k = blockIdx.x * 4 + wv;
    const float4 v = *reinterpret_cast<const float4*>(emb + (size_t)k * 256 + ln * 4);
    float s = v.x * v.x + v.y * v.y + v.z * v.z + v.w * v.w;
#pragma unroll
    for (int off = 32; off > 0; off >>= 1) s += __shfl_xor(s, off);
    if (ln == 0) enorm[k] = s;
}

// ---------------- kernel 1: argmin (dq-specialized) ----------------
// 256 thr = 4 waves. Wave wv owns rows wv*16+m (m=0..15).
// Lane: dq = tid&3 (d-quarter), tx = (tid>>2)&15 (code lane).
// Chunk kc (64 codes): thread's codes = kc*64 + c*16 + tx, c=0..3.
// acc[m][c] = partial dot over d in quarter dq; quad __shfl_xor combines.
__global__ __launch_bounds__(256, 1)
void argmin_kernel(const float* __restrict__ z, const float* __restrict__ emb,
                   const float* __restrict__ enorm_g, float* __restrict__ idx_out) {
    __shared__ float z_lds[16384];   // [row][d] linear, 64 KB
    __shared__ float znbuf[64];

    const int tid = threadIdx.x;
    const int dq = tid & 3;
    const int tx = (tid >> 2) & 15;
    const int wv = tid >> 6;
    const int ln = tid & 63;

    const float* zblk = z + (size_t)blockIdx.x * 16384;

    // ---- DMA z tile to LDS (linear dest = linear source) ----
#pragma unroll
    for (int c = 0; c < 16; ++c) {
        const int off = c * 1024 + wv * 256 + ln * 4;
        gload16(zblk + off, &z_lds[off]);
    }

    // ---- per-row |z|^2 from global (L2-hit; overlaps DMA) ----
#pragma unroll
    for (int it = 0; it < 16; ++it) {
        const int r = it * 4 + wv;
        const float4 v = *reinterpret_cast<const float4*>(zblk + r * 256 + ln * 4);
        float s = fmaf(v.x, v.x, fmaf(v.y, v.y, fmaf(v.z, v.z, v.w * v.w)));
#pragma unroll
        for (int o = 32; o > 0; o >>= 1) s += __shfl_xor(s, o);
        if (ln == 0) znbuf[r] = s;
    }

    WAITVM(0);
    __syncthreads();   // z_lds + znbuf ready; no barriers after this point

    float best[16];
    int   bidx[16];
#pragma unroll
    for (int m = 0; m < 16; ++m) { best[m] = 3.4e38f; bidx[m] = 0; }

    const int zbase = wv * 4096 + dq * 4;   // row wv*16, quarter dq

#pragma unroll 1
    for (int kc = 0; kc < 16; ++kc) {       // 64 codes per chunk
        float acc[16][4];
#pragma unroll
        for (int m = 0; m < 16; ++m)
#pragma unroll
            for (int c = 0; c < 4; ++c) acc[m][c] = 0.f;

        float en[4];
#pragma unroll
        for (int c = 0; c < 4; ++c) en[c] = enorm_g[kc * 64 + c * 16 + tx];

#pragma unroll 1
        for (int dc = 0; dc < 16; ++dc) {
            // e: 4 float4 global loads; each dq-quad consumes a contiguous 64B line
            float4 e[4];
#pragma unroll
            for (int c = 0; c < 4; ++c)
                e[c] = *reinterpret_cast<const float4*>(
                    emb + (size_t)(kc * 64 + c * 16 + tx) * 256 + dc * 16 + dq * 4);
#pragma unroll
            for (int m = 0; m < 16; ++m) {
                const float4 a = *reinterpret_cast<const float4*>(
                    &z_lds[zbase + m * 256 + dc * 16]);   // 16-lane broadcast read
#pragma unroll
                for (int c = 0; c < 4; ++c) {
                    acc[m][c] = fmaf(a.x, e[c].x, acc[m][c]);
                    acc[m][c] = fmaf(a.y, e[c].y, acc[m][c]);
                    acc[m][c] = fmaf(a.z, e[c].z, acc[m][c]);
                    acc[m][c] = fmaf(a.w, e[c].w, acc[m][c]);
                }
            }
        }

        // ---- chunk epilogue: quad combine, dist, argmin ----
#pragma unroll
        for (int m = 0; m < 16; ++m) {
            const float znm = znbuf[wv * 16 + m];
#pragma unroll
            for (int c = 0; c < 4; ++c) {
                float dot = acc[m][c];
                dot += __shfl_xor(dot, 1);
                dot += __shfl_xor(dot, 2);
                const float dist = fmaf(-2.f, dot, znm + en[c]);
                const int col = kc * 64 + c * 16 + tx;   // ascending scan order
                if (dist < best[m]) { best[m] = dist; bidx[m] = col; }
            }
        }
    }

    // ---- cross-tx butterfly (lane bits 2..5), lowest-index tie-break ----
#pragma unroll
    for (int m = 0; m < 16; ++m) {
#pragma unroll
        for (int off = 4; off < 64; off <<= 1) {
            const float ov = __shfl_xor(best[m], off);
            const int   oi = __shfl_xor(bidx[m], off);
            if (ov < best[m] || (ov == best[m] && oi < bidx[m])) {
                best[m] = ov; bidx[m] = oi;
            }
        }
    }
    if (ln == 0) {
        float* o = idx_out + (size_t)blockIdx.x * 64 + wv * 16;
#pragma unroll
        for (int m = 0; m < 16; ++m) o[m] = (float)bidx[m];
    }
}

// ---------------- kernel 2: gather + quantized output + loss partials ----------------
__global__ __launch_bounds__(256)
void gather_kernel(const float* __restrict__ z, const float* __restrict__ emb,
                   const float* __restrict__ idx_f, float* __restrict__ q_out,
                   float* __restrict__ partials) {
    const int wv = threadIdx.x >> 6, ln = threadIdx.x & 63;
    float lsum = 0.f;
#pragma unroll
    for (int i = 0; i < 16; ++i) {
        const size_t row = (size_t)blockIdx.x * 64 + i * 4 + wv;
        const int kidx = (int)idx_f[row];
        const float4 e4 = *reinterpret_cast<const float4*>(emb + (size_t)kidx * 256 + ln * 4);
        const float4 z4 = *reinterpret_cast<const float4*>(z + row * 256 + ln * 4);
        *reinterpret_cast<float4*>(q_out + row * 256 + ln * 4) = e4;  // quantized_st == quantized
        const float dx = e4.x - z4.x, dy = e4.y - z4.y, dz = e4.z - z4.z, dw = e4.w - z4.w;
        lsum += dx * dx + dy * dy + dz * dz + dw * dw;
    }
#pragma unroll
    for (int off = 32; off > 0; off >>= 1) lsum += __shfl_xor(lsum, off);
    __shared__ float red[4];
    if (ln == 0) red[wv] = lsum;
    __syncthreads();
    if (threadIdx.x == 0) partials[blockIdx.x] = red[0] + red[1] + red[2] + red[3];
}

// ---------------- kernel 3: deterministic loss reduction ----------------
__global__ __launch_bounds__(256)
void loss_kernel(const float* __restrict__ partials, float* __restrict__ loss_out) {
    const int tid = threadIdx.x;
    float s = partials[tid] + partials[tid + 256] + partials[tid + 512] + partials[tid + 768];
#pragma unroll
    for (int off = 32; off > 0; off >>= 1) s += __shfl_xor(s, off);
    __shared__ float red[4];
    if ((tid & 63) == 0) red[tid >> 6] = s;
    __syncthreads();
    if (tid == 0)
        loss_out[0] = (red[0] + red[1] + red[2] + red[3]) * (1.25f / 16777216.0f);
}

extern "C" void kernel_launch(void* const* d_in, const int* in_sizes, int n_in,
                              void* d_out, int out_size, void* d_ws, size_t ws_size,
                              hipStream_t stream) {
    const float* z   = (const float*)d_in[0];
    const float* emb = (const float*)d_in[1];
    float* out      = (float*)d_out;
    float* q_out    = out;                       // 16,777,216 floats
    float* loss_out = out + 16777216;            // 1 float
    float* idx_out  = out + 16777217;            // 65,536 floats
    float* enorm    = (float*)d_ws;              // 1024 floats
    float* partials = (float*)d_ws + 1024;       // 1024 floats

    enorm_kernel<<<256, 256, 0, stream>>>(emb, enorm);
    argmin_kernel<<<1024, 256, 0, stream>>>(z, emb, enorm, idx_out);
    gather_kernel<<<1024, 256, 0, stream>>>(z, emb, idx_out, q_out, partials);
    loss_kernel<<<1, 256, 0, stream>>>(partials, loss_out);
}